// Round 4
// baseline (640.861 us; speedup 1.0000x reference)
//
#include <hip/hip_runtime.h>

// ---------------------------------------------------------------------------
// CConv: out[n,o] = sum_{m,s,i} sel[n,m,s] * W[s,o,i] * feat[idx[n,m], i]
// featconv: feat fp32 -> bf16 (12.8 MB, L2/L3-resident for the gather)
// Phase 1: t[n,s,i] = sum_m sel*pf per-n 32x32x16 MFMA; sel B-frags gathered
//          direct from global (no selT LDS -> 5 blocks/CU); pipelined gathers;
//          acc -> LDS (16B-granule XOR swizzle) -> coalesced T stores.
// Phase 2: barrier-free, LDS-free. Wave owns 32 n x 128 o; A b128 direct from
//          T (16x64B coalesced), B b128 direct from L2-hot Wt; 16 MFMA / K=32.
// ---------------------------------------------------------------------------

#define N_CHI 128
#define N_SP  27
#define N_M   32
#define KDIM  (N_SP * N_CHI)      // 3456
#define SEL_STRIDE (N_M * N_SP)   // 864

typedef short s16x8 __attribute__((ext_vector_type(8)));
typedef s16x8 __attribute__((may_alias)) s16x8_a;
typedef unsigned short u16x8 __attribute__((ext_vector_type(8)));
typedef u16x8 __attribute__((may_alias)) u16x8_a;
typedef unsigned short u16x4 __attribute__((ext_vector_type(4)));
typedef u16x4 __attribute__((may_alias)) u16x4_a;
typedef unsigned int u32x2 __attribute__((ext_vector_type(2)));
typedef u32x2 __attribute__((may_alias)) u32x2_a;
typedef float f32x4 __attribute__((ext_vector_type(4)));
typedef f32x4 __attribute__((may_alias)) f32x4_a;
typedef float f32x16 __attribute__((ext_vector_type(16)));

static __device__ __forceinline__ unsigned short f2bf(float f) {
  unsigned int u = __float_as_uint(f);
  u += 0x7FFFu + ((u >> 16) & 1u);   // round-to-nearest-even (inputs finite)
  return (unsigned short)(u >> 16);
}

// --------------------------------------------------------------------------
// Kernel 0a: W [27][128o*128i] fp32 -> Wt [o][s*128+i] bf16  (k contiguous)
// --------------------------------------------------------------------------
__global__ __launch_bounds__(128) void wconv_kernel(const float* __restrict__ w,
                                                    unsigned short* __restrict__ Wt) {
  const int s = blockIdx.x;    // 27
  const int o = blockIdx.y;    // 128
  const int i = threadIdx.x;   // 128
  Wt[((size_t)o * N_SP + s) * N_CHI + i] = f2bf(w[((size_t)s * 128 + o) * N_CHI + i]);
}

// --------------------------------------------------------------------------
// Kernel 0b: feat fp32 [N*128] -> featb bf16
// --------------------------------------------------------------------------
__global__ __launch_bounds__(256) void featconv_kernel(
    const float* __restrict__ feat, unsigned short* __restrict__ featb, int total4) {
  const int t = blockIdx.x * 256 + threadIdx.x;
  if (t < total4) {
    f32x4 v = ((const f32x4_a*)feat)[t];
    u16x4 o;
#pragma unroll
    for (int j = 0; j < 4; ++j) o[j] = f2bf(v[j]);
    ((u16x4_a*)featb)[t] = o;
  }
}

// --------------------------------------------------------------------------
// Kernel 1: per-n  t^T[i][s] = pf^T(128x32m) x sel(32m x 32s)  via 32x32x16.
// sel B-frag loaded direct: bf[j] = sel[n][m=q*8+j(+16)][s=col] (2x ~108B
// segments per instr). Gathers software-pipelined across the 4 i-tiles.
// acc -> tbuf (phys16 = b16 ^ (col&15)) -> 7 coalesced b128 stores.
// --------------------------------------------------------------------------
__global__ __launch_bounds__(256) void phase1_kernel(
    const unsigned short* __restrict__ featb, const float* __restrict__ sel,
    const int* __restrict__ nidx, unsigned short* __restrict__ T,
    int nbase, int nend) {
  __shared__ __align__(16) unsigned short tbuf[4][N_SP * 128];  // 27648 B
  const int wave = threadIdx.x >> 6;
  const int lane = threadIdx.x & 63;
  const int n = nbase + (int)blockIdx.x * 4 + wave;
  if (n >= nend) return;                 // wave-private LDS: no barriers needed
  unsigned short* tb = tbuf[wave];

  const int q = lane >> 5;     // 0..1  (K-half)
  const int col = lane & 31;   // A-row (i_local) == B-col (s)
  const int colc = (col < N_SP) ? col : N_SP - 1;   // clamp (in-bounds load)

  // B fragments direct from global (lanes col 0..26 coalesced within a row)
  const float* selp = sel + (size_t)n * SEL_STRIDE;
  s16x8 bf0, bf1;
#pragma unroll
  for (int j = 0; j < 8; ++j) {
    float v0 = selp[(q * 8 + j) * N_SP + colc];        // m = q*8+j
    float v1 = selp[(16 + q * 8 + j) * N_SP + colc];   // m = 16+q*8+j
    bf0[j] = (short)((col < N_SP) ? f2bf(v0) : (unsigned short)0);
    bf1[j] = (short)((col < N_SP) ? f2bf(v1) : (unsigned short)0);
  }

  // neighbor row element bases for this lane's k positions: m = ks*16+q*8+j
  const int* ip = nidx + (size_t)n * N_M;
  size_t roff[16];
#pragma unroll
  for (int ks = 0; ks < 2; ++ks)
#pragma unroll
    for (int j = 0; j < 8; ++j)
      roff[ks * 8 + j] = (size_t)ip[ks * 16 + q * 8 + j] << 7;   // *128

  // software-pipelined gather over the 4 i-tiles
  unsigned short fv[2][16];
#pragma unroll
  for (int t = 0; t < 16; ++t) fv[0][t] = featb[roff[t] + col];   // ti=0
#pragma unroll
  for (int ti = 0; ti < 4; ++ti) {
    const int cur = ti & 1;
    if (ti < 3) {
      const int icol = (ti + 1) * 32 + col;
#pragma unroll
      for (int t = 0; t < 16; ++t) fv[cur ^ 1][t] = featb[roff[t] + icol];
    }
    s16x8 af0, af1;
#pragma unroll
    for (int j = 0; j < 8; ++j) {
      af0[j] = (short)fv[cur][j];
      af1[j] = (short)fv[cur][8 + j];
    }
    f32x16 acc = {0.f, 0.f, 0.f, 0.f, 0.f, 0.f, 0.f, 0.f,
                  0.f, 0.f, 0.f, 0.f, 0.f, 0.f, 0.f, 0.f};
    acc = __builtin_amdgcn_mfma_f32_32x32x16_bf16(af0, bf0, acc, 0, 0, 0);
    acc = __builtin_amdgcn_mfma_f32_32x32x16_bf16(af1, bf1, acc, 0, 0, 0);
    if (col < N_SP) {  // s = col; drop padding rows
#pragma unroll
      for (int g = 0; g < 4; ++g) {  // i = ti*32 + 8g + 4q + {0..3}
        const int b16 = ti * 4 + g;
        const int phys16 = b16 ^ (col & 15);
        u32x2 pk;
        pk[0] = (unsigned int)f2bf(acc[4 * g + 0]) | ((unsigned int)f2bf(acc[4 * g + 1]) << 16);
        pk[1] = (unsigned int)f2bf(acc[4 * g + 2]) | ((unsigned int)f2bf(acc[4 * g + 3]) << 16);
        *(u32x2_a*)&tb[col * 128 + phys16 * 8 + q * 4] = pk;
      }
    }
  }

  // coalesced store: 432 16B blocks, 7 wave-iters
  unsigned short* Tn = T + (size_t)(n - nbase) * KDIM;
#pragma unroll
  for (int it = 0; it < 7; ++it) {
    const int P = it * 64 + lane;      // block id, 0..431
    if (P < 432) {
      const int c = P >> 4;                    // s, 0..26
      const int b16 = P & 15;
      const int phys16 = b16 ^ (c & 15);
      *(u16x8_a*)&Tn[(size_t)P * 8] = *(const u16x8_a*)&tb[c * 128 + phys16 * 8];
    }
  }
}

// --------------------------------------------------------------------------
// Kernel 2: barrier-free GEMM. Wave owns 32 rows x 128 o, loops K in 32-steps:
// A0/A1 b128 from T (16 rows x 64B coalesced), B[8] b128 from Wt (L2/L1-hot,
// shared by all waves), 16 MFMA. No LDS, no __syncthreads.
// --------------------------------------------------------------------------
__global__ __launch_bounds__(256) void phase2_kernel(
    const unsigned short* __restrict__ T, const unsigned short* __restrict__ Wt,
    float* __restrict__ out, int nbase, int N) {
  const int lane = threadIdx.x & 63;
  const int wave = threadIdx.x >> 6;
  const int q = lane >> 4, l16 = lane & 15;
  const size_t rb = (size_t)blockIdx.x * 128 + (size_t)wave * 32;  // T-local row

  const unsigned short* a0 = T + (rb + l16) * KDIM + q * 8;
  const unsigned short* a1 = a0 + (size_t)16 * KDIM;
  const unsigned short* bp = Wt + (size_t)l16 * KDIM + q * 8;

  f32x4 acc[2][8];
#pragma unroll
  for (int g = 0; g < 2; ++g)
#pragma unroll
    for (int nt = 0; nt < 8; ++nt) acc[g][nt] = (f32x4){0.f, 0.f, 0.f, 0.f};

#pragma unroll 2
  for (int kt = 0; kt < KDIM / 32; ++kt) {   // 108 iters
    const int k = kt * 32;
    const s16x8 A0 = *(const s16x8_a*)(a0 + k);
    const s16x8 A1 = *(const s16x8_a*)(a1 + k);
    s16x8 B[8];
#pragma unroll
    for (int nt = 0; nt < 8; ++nt)
      B[nt] = *(const s16x8_a*)(bp + (size_t)nt * 16 * KDIM + k);
#pragma unroll
    for (int nt = 0; nt < 8; ++nt) {
      acc[0][nt] = __builtin_amdgcn_mfma_f32_16x16x32_bf16(A0, B[nt], acc[0][nt], 0, 0, 0);
      acc[1][nt] = __builtin_amdgcn_mfma_f32_16x16x32_bf16(A1, B[nt], acc[1][nt], 0, 0, 0);
    }
  }

#pragma unroll
  for (int g = 0; g < 2; ++g) {
    const long growb = (long)nbase + (long)rb + g * 16 + q * 4;
#pragma unroll
    for (int r = 0; r < 4; ++r) {
      const long grow = growb + r;
      if (grow < N) {
#pragma unroll
        for (int nt = 0; nt < 8; ++nt)
          out[grow * 128 + nt * 16 + l16] = acc[g][nt][r];
      }
    }
  }
}

// --------------------------------------------------------------------------
extern "C" void kernel_launch(void* const* d_in, const int* in_sizes, int n_in,
                              void* d_out, int out_size, void* d_ws, size_t ws_size,
                              hipStream_t stream) {
  const float* feat = (const float*)d_in[0];   // [N,128] fp32
  const float* sel  = (const float*)d_in[1];   // [N,32,27] fp32
  const float* wgt  = (const float*)d_in[2];   // [27,128*128] fp32
  const int*   nidx = (const int*)d_in[3];     // [N,32] int32
  float* out = (float*)d_out;                  // [N,128,1] fp32
  const int N = in_sizes[0] / N_CHI;           // 50000
  const int total = in_sizes[0];               // N*128

  unsigned short* Wt = (unsigned short*)d_ws;          // 442368 elems
  const size_t WT_ELEMS = (size_t)128 * KDIM;
  unsigned short* featb = Wt + WT_ELEMS;               // N*128 bf16
  const size_t FB_ELEMS = (size_t)N * N_CHI;
  unsigned short* T = featb + FB_ELEMS;                // chunked [NC,3456] bf16

  wconv_kernel<<<dim3(N_SP, 128), 128, 0, stream>>>(wgt, Wt);
  featconv_kernel<<<dim3((unsigned)((total / 4 + 255) / 256)), 256, 0, stream>>>(
      feat, featb, total / 4);

  const size_t head = (WT_ELEMS + FB_ELEMS) * 2;
  const size_t bytes_for_T = (ws_size > head) ? (ws_size - head) : 0;
  long cap_rows = (long)(bytes_for_T / ((size_t)KDIM * 2));
  long NC = (cap_rows / 128) * 128;
  const long Nfull = (((long)N + 127) / 128) * 128;
  if (NC > Nfull) NC = Nfull;
  if (NC <= 0) return;  // workspace too small (not expected)

  for (long nb = 0; nb < N; nb += NC) {
    long rows = (long)N - nb;
    if (rows > NC) rows = NC;
    const long rows128 = ((rows + 127) / 128) * 128;  // <= NC
    phase1_kernel<<<dim3((unsigned)((rows + 3) / 4)), 256, 0, stream>>>(
        featb, sel, nidx, T, (int)nb, (int)(nb + rows));
    phase2_kernel<<<dim3((unsigned)(rows128 / 128)), 256, 0, stream>>>(
        T, Wt, out, (int)nb, N);
  }
}